// Round 11
// baseline (337.879 us; speedup 1.0000x reference)
//
#include <hip/hip_runtime.h>
#include <hip/hip_bf16.h>

// ---- problem constants (fixed by the reference) ----
#define HS   1024
#define FF   4096
#define NH   16
#define HD   64
#define SEQ  2048
#define BSZ  2
#define MROWS (BSZ * SEQ)   // 4096 token rows
#define EPS  1e-5f
#define QKV_STRIDE (3 * HS) // fused qkv activation row stride

typedef float f32x4  __attribute__((ext_vector_type(4)));
typedef short bf16x8 __attribute__((ext_vector_type(8)));

#if __has_builtin(__builtin_amdgcn_exp2f)
#define EXP2(x) __builtin_amdgcn_exp2f(x)
#else
#define EXP2(x) exp2f(x)
#endif

__device__ __forceinline__ unsigned short f2bf(float x) {
  unsigned int u = __float_as_uint(x);
  u += 0x7fffu + ((u >> 16) & 1u);   // round-to-nearest-even
  return (unsigned short)(u >> 16);
}

__device__ __forceinline__ float bf2f(unsigned short u) {
  return __uint_as_float((unsigned int)u << 16);
}

// pack two floats -> packed bf16 pair (low = a, high = b)
__device__ __forceinline__ unsigned int pkbf(float a, float b) {
  union { __hip_bfloat162 h; unsigned int u; } x;
  x.h = __float22bfloat162_rn(float2{a, b});
  return x.u;
}

// async global->LDS, 16 B per lane; LDS dest = wave-uniform base + lane*16
__device__ __forceinline__ void async16(const ushort* g, ushort* lds) {
  __builtin_amdgcn_global_load_lds(
      (const __attribute__((address_space(1))) unsigned int*)g,
      (__attribute__((address_space(3))) unsigned int*)lds, 16, 0, 0);
}

#define BARSB { __builtin_amdgcn_s_barrier(); __builtin_amdgcn_sched_barrier(0); }

// ======================================================================
// 8-phase 256x256 bf16 GEMM (T2+T3+T4+T5 port), 512 thr = 8 waves
// (2M x 4N).  BK=64; one loop iter = 2 K-tiles (even->buf0, odd->buf1).
// Verified round-6: QKV+FF1 -20.7us vs m97 structure.
// VTRANS epilogue (round-8, verified): QKV's V-columns write transposed.
// PARTIAL split-K mode (round-10, verified): blockIdx.z selects K-range
// [z*kSplit, +kSplit); kSplit multiple of 128 preserves tile parity.
// ======================================================================
#define QUAD(kt, MH, NH)                                                      \
  {                                                                           \
    const ushort* As_ = &smem[(size_t)((kt) & 1) * 32768];                    \
    const ushort* Bs_ = As_ + 16384;                                          \
    bf16x8 af[4][2], bfr[2][2];                                               \
    _Pragma("unroll")                                                         \
    for (int mt = 0; mt < 4; ++mt)                                            \
      _Pragma("unroll")                                                       \
      for (int s = 0; s < 2; ++s) {                                           \
        const int m = wr * 128 + (MH) * 64 + mt * 16 + lr;                    \
        af[mt][s] = *(const bf16x8*)&As_[(size_t)m * 64 +                     \
                                         (((s * 4 + lg) ^ (m & 7)) * 8)];     \
      }                                                                       \
    _Pragma("unroll")                                                         \
    for (int nj = 0; nj < 2; ++nj)                                            \
      _Pragma("unroll")                                                       \
      for (int s = 0; s < 2; ++s) {                                           \
        const int n = wc * 64 + (NH) * 32 + nj * 16 + lr;                     \
        bfr[nj][s] = *(const bf16x8*)&Bs_[(size_t)n * 64 +                    \
                                          (((s * 4 + lg) ^ (n & 7)) * 8)];    \
      }                                                                       \
    __builtin_amdgcn_s_setprio(1);                                            \
    _Pragma("unroll")                                                         \
    for (int s = 0; s < 2; ++s)                                               \
      _Pragma("unroll")                                                       \
      for (int mt = 0; mt < 4; ++mt)                                          \
        _Pragma("unroll")                                                     \
        for (int nj = 0; nj < 2; ++nj)                                        \
          acc[(MH) * 4 + mt][(NH) * 2 + nj] =                                 \
              __builtin_amdgcn_mfma_f32_16x16x32_bf16(                        \
                  af[mt][s], bfr[nj][s], acc[(MH) * 4 + mt][(NH) * 2 + nj],   \
                  0, 0, 0);                                                   \
    __builtin_amdgcn_s_setprio(0);                                            \
  }

template <bool RELU, bool VTRANS, bool PARTIAL>
__global__ __launch_bounds__(512, 2) void gemm8_bf16_kernel(
    const ushort* __restrict__ A, const ushort* __restrict__ Bt,
    const float* __restrict__ bias, ushort* __restrict__ C,
    ushort* __restrict__ VTg,
    float* __restrict__ P0, float* __restrict__ P1, float* __restrict__ P2,
    int M, int N, int K, int kSplit)
{
  __shared__ ushort smem[65536];          // 128 KB
  const int tid = threadIdx.x;
  const int wv = tid >> 6, ln = tid & 63;
  const int wr = wv >> 2, wc = wv & 3;
  const int lr = ln & 15, lg = ln >> 4;
  const int rr = ln >> 3, cc = ln & 7;

  const unsigned nxy = gridDim.x * gridDim.y;
  unsigned id = blockIdx.y * gridDim.x + blockIdx.x;
  id = (id & 7) * (nxy >> 3) + (id >> 3);
  const int bn = id % gridDim.x, bm = id / gridDim.x;

  int kBeg = 0, kEnd = K;
  if (PARTIAL) {
    kBeg = blockIdx.z * kSplit;
    kEnd = kBeg + kSplit; if (kEnd > K) kEnd = K;
  }
  const int jBeg = kBeg >> 7, jEnd = kEnd >> 7;

  f32x4 acc[8][4];
#pragma unroll
  for (int i = 0; i < 8; ++i)
#pragma unroll
    for (int j = 0; j < 4; ++j) acc[i][j] = (f32x4){0.f, 0.f, 0.f, 0.f};

  // stage A-half h of tile kt: calls tt = h, h+2 (rows [tt*64, +64))
  auto stA = [&](int kt, int h) {
#pragma unroll
    for (int u = 0; u < 2; ++u) {
      const int tt = h + u * 2;
      const int R = tt * 64 + wv * 8 + rr;
      async16(A + (size_t)(bm * 256 + R) * K + kt * 64 + ((cc ^ (R & 7)) * 8),
              &smem[(size_t)(kt & 1) * 32768 + (size_t)(tt * 64 + wv * 8) * 64]);
    }
  };
  // stage B-half h of tile kt: calls tt = 2h, 2h+1 (rows [h*128, +128))
  auto stB = [&](int kt, int h) {
#pragma unroll
    for (int u = 0; u < 2; ++u) {
      const int tt = h * 2 + u;
      const int R = tt * 64 + wv * 8 + rr;
      async16(Bt + (size_t)(bn * 256 + R) * K + kt * 64 + ((cc ^ (R & 7)) * 8),
              &smem[(size_t)(kt & 1) * 32768 + 16384 + (size_t)(tt * 64 + wv * 8) * 64]);
    }
  };

  // prologue: first tile full + second tile A02 (10 loads/thread).
  const int tP = 2 * jBeg;
  stA(tP, 0); stA(tP, 1); stB(tP, 0); stB(tP, 1); stA(tP + 1, 0);

  for (int j = jBeg; j < jEnd; ++j) {
    const int t0 = 2 * j, t1 = t0 + 1;
    const bool nx = (j + 1 < jEnd);
    // ph0: gate for tile t0 reads
    BARSB;
    stA(t1, 1);
    asm volatile("s_waitcnt vmcnt(4)" ::: "memory");
    BARSB;
    QUAD(t0, 0, 0);
    // ph1
    BARSB; stB(t1, 0); QUAD(t0, 0, 1);
    // ph2 (A02 of buf0 dead after ph1)
    BARSB; if (nx) stA(t0 + 2, 0); QUAD(t0, 1, 0);
    // ph3
    BARSB; stB(t1, 1); QUAD(t0, 1, 1);
    // ph4: gate for tile t1 reads
    BARSB;
    if (nx) {
      stA(t0 + 2, 1);
      asm volatile("s_waitcnt vmcnt(2)" ::: "memory");
    } else {
      asm volatile("s_waitcnt vmcnt(0)" ::: "memory");
    }
    BARSB;
    QUAD(t1, 0, 0);
    // ph5
    BARSB; if (nx) stB(t0 + 2, 0); QUAD(t1, 0, 1);
    // ph6
    BARSB; if (nx) stB(t0 + 2, 1); QUAD(t1, 1, 0);
    // ph7 (A02 of buf1 dead after ph5)
    BARSB; if (nx) stA(t0 + 3, 0); QUAD(t1, 1, 1);
  }

  const int gm0 = bm * 256 + wr * 128;
  const int gn0 = bn * 256 + wc * 64;

  if (PARTIAL) {
    float* Cp = (blockIdx.z == 0) ? P0 : (blockIdx.z == 1) ? P1 : P2;
#pragma unroll
    for (int i = 0; i < 8; ++i) {
#pragma unroll
      for (int r = 0; r < 4; ++r) {
        const size_t row = (size_t)(gm0 + i * 16 + lg * 4 + r);
#pragma unroll
        for (int j = 0; j < 4; ++j)
          Cp[row * N + gn0 + j * 16 + lr] = acc[i][j][r];
      }
    }
    return;
  }

  // epilogue: bias + (relu) + bf16 store
  float bs4[4];
#pragma unroll
  for (int j = 0; j < 4; ++j) bs4[j] = bias[gn0 + j * 16 + lr];

  if (VTRANS && gn0 >= 2 * HS) {
    // V columns: write transposed to VTg[(b*16+h)*64+d][seq].
#pragma unroll
    for (int i = 0; i < 8; ++i) {
#pragma unroll
      for (int j = 0; j < 4; ++j) {
        const int col = gn0 - 2 * HS + j * 16 + lr;   // h*64 + d
        const int rowb = gm0 + i * 16 + lg * 4;
        const int bb = rowb >> 11;                    // batch
        const int seq = rowb & (SEQ - 1);
        ushort4 o;
        o.x = f2bf(acc[i][j][0] + bs4[j]);
        o.y = f2bf(acc[i][j][1] + bs4[j]);
        o.z = f2bf(acc[i][j][2] + bs4[j]);
        o.w = f2bf(acc[i][j][3] + bs4[j]);
        *(ushort4*)&VTg[((size_t)(bb * NH + (col >> 6)) * 64 + (col & 63)) * SEQ + seq] = o;
      }
    }
  } else {
#pragma unroll
    for (int i = 0; i < 8; ++i) {
#pragma unroll
      for (int r = 0; r < 4; ++r) {
        const size_t row = (size_t)(gm0 + i * 16 + lg * 4 + r);
#pragma unroll
        for (int j = 0; j < 4; ++j) {
          float val = acc[i][j][r] + bs4[j];
          if (RELU) val = fmaxf(val, 0.f);
          C[row * N + gn0 + j * 16 + lr] = f2bf(val);
        }
      }
    }
  }
}

// ======================================================================
// bf16 MFMA GEMM (m97 structure): C = A@B + bias, Bt = B^T [N][K].
// Used for Wo (64x128, 512 blocks = 2/CU).
// ======================================================================
template <int TBM, int TBN, bool RELU, bool OUT_BF16, bool PARTIAL>
__global__ __launch_bounds__(256) void gemm_bf16_kernel(
    const ushort* __restrict__ A, const ushort* __restrict__ Bt,
    const float* __restrict__ bias, void* __restrict__ Cout,
    int M, int N, int K, int kLen, size_t zstride)
{
  constexpr int MI = TBM / 32;
  constexpr int NJ = TBN / 32;
  __shared__ ushort As[TBM * 64];
  __shared__ ushort Bs[TBN * 64];

  const int tid = threadIdx.x;
  const int wv = tid >> 6, ln = tid & 63;

  const unsigned nxy = gridDim.x * gridDim.y;
  unsigned id = blockIdx.y * gridDim.x + blockIdx.x;
  id = (id & 7) * (nxy >> 3) + (id >> 3);
  const int bn = id % gridDim.x, bm = id / gridDim.x;

  const int lr = ln & 15;
  const int lg = ln >> 4;
  const int mrow_base = (wv >> 1) * (TBM / 2);
  const int ncol_base = (wv & 1) * (TBN / 2);

  f32x4 acc[MI][NJ];
#pragma unroll
  for (int i = 0; i < MI; ++i)
#pragma unroll
    for (int j = 0; j < NJ; ++j) acc[i][j] = (f32x4){0.f, 0.f, 0.f, 0.f};

  const int rr = ln >> 3, cc = ln & 7;
  const int kBeg = blockIdx.z * kLen, kEnd = kBeg + kLen;

  for (int k0 = kBeg; k0 < kEnd; k0 += 64) {
    __syncthreads();
#pragma unroll
    for (int t = 0; t < TBM / 32; ++t) {
      const int R = wv * (TBM / 4) + t * 8 + rr;
      const int c = cc ^ (R & 7);
      async16(A + (size_t)(bm * TBM + R) * K + k0 + c * 8,
              &As[(size_t)(wv * (TBM / 4) + t * 8) * 64]);
    }
#pragma unroll
    for (int t = 0; t < TBN / 32; ++t) {
      const int R = wv * (TBN / 4) + t * 8 + rr;
      const int c = cc ^ (R & 7);
      async16(Bt + (size_t)(bn * TBN + R) * K + k0 + c * 8,
              &Bs[(size_t)(wv * (TBN / 4) + t * 8) * 64]);
    }
    __syncthreads();

#pragma unroll
    for (int s = 0; s < 2; ++s) {
      bf16x8 a[MI], b[NJ];
#pragma unroll
      for (int i = 0; i < MI; ++i) {
        const int m = mrow_base + i * 16 + lr;
        a[i] = *(const bf16x8*)&As[(size_t)m * 64 + (((s * 4 + lg) ^ (m & 7)) * 8)];
      }
#pragma unroll
      for (int j = 0; j < NJ; ++j) {
        const int n = ncol_base + j * 16 + lr;
        b[j] = *(const bf16x8*)&Bs[(size_t)n * 64 + (((s * 4 + lg) ^ (n & 7)) * 8)];
      }
#pragma unroll
      for (int i = 0; i < MI; ++i)
#pragma unroll
        for (int j = 0; j < NJ; ++j)
          acc[i][j] = __builtin_amdgcn_mfma_f32_16x16x32_bf16(a[i], b[j], acc[i][j], 0, 0, 0);
    }
  }

  const int gm0 = bm * TBM + mrow_base;
  const int gn0 = bn * TBN + ncol_base;

  if (PARTIAL) {
    float* Cp = (float*)Cout + (size_t)blockIdx.z * zstride;
#pragma unroll
    for (int i = 0; i < MI; ++i)
#pragma unroll
      for (int r = 0; r < 4; ++r) {
        const size_t row = (size_t)(gm0 + i * 16 + lg * 4 + r);
#pragma unroll
        for (int j = 0; j < NJ; ++j)
          Cp[row * N + gn0 + j * 16 + lr] = acc[i][j][r];
      }
  } else {
    float bs4[NJ];
#pragma unroll
    for (int j = 0; j < NJ; ++j) bs4[j] = bias[gn0 + j * 16 + lr];
    float* Cf = (float*)Cout;
    ushort* Cb = (ushort*)Cout;
#pragma unroll
    for (int i = 0; i < MI; ++i) {
#pragma unroll
      for (int r = 0; r < 4; ++r) {
        const size_t row = (size_t)(gm0 + i * 16 + lg * 4 + r);
#pragma unroll
        for (int j = 0; j < NJ; ++j) {
          float val = acc[i][j][r] + bs4[j];
          if (RELU) val = fmaxf(val, 0.f);
          const size_t idx = row * N + gn0 + j * 16 + lr;
          if (OUT_BF16) Cb[idx] = f2bf(val);
          else          Cf[idx] = val;
        }
      }
    }
  }
}

// ======================================================================
// Fused prep kernel: 6 weight transposes (fp32 [K][N] -> bf16 [N][K]),
// bias concat, x -> bf16, mask*log2e (f32, for exp2 softmax).
// ======================================================================
__device__ __forceinline__ void transpose_tile(
    const float* __restrict__ W, ushort* __restrict__ Wt,
    int K, int N, int n0, int k0, int tid, ushort (*T)[72])
{
#pragma unroll
  for (int t = 0; t < 4; ++t) {
    const int r = t * 16 + (tid >> 4);
    const int c = (tid & 15) * 4;
    const float4 w = *(const float4*)&W[(size_t)(k0 + r) * N + n0 + c];
    T[c + 0][r] = f2bf(w.x); T[c + 1][r] = f2bf(w.y);
    T[c + 2][r] = f2bf(w.z); T[c + 3][r] = f2bf(w.w);
  }
  __syncthreads();
#pragma unroll
  for (int t = 0; t < 4; ++t) {
    const int n = t * 16 + (tid >> 4);
    const int kc = (tid & 15) * 4;
    ushort4 o;
    o.x = T[n][kc]; o.y = T[n][kc + 1]; o.z = T[n][kc + 2]; o.w = T[n][kc + 3];
    *(ushort4*)&Wt[(size_t)(n0 + n) * K + k0 + kc] = o;
  }
}

__global__ __launch_bounds__(256) void prep_kernel(
    const float* __restrict__ Wq, const float* __restrict__ Wk,
    const float* __restrict__ Wv, const float* __restrict__ Wo,
    const float* __restrict__ W1, const float* __restrict__ W2,
    const float* __restrict__ bq, const float* __restrict__ bk,
    const float* __restrict__ bv, const float* __restrict__ x,
    const float* __restrict__ mask,
    ushort* __restrict__ Wqkvt, ushort* __restrict__ Wot,
    ushort* __restrict__ W1t, ushort* __restrict__ W2t,
    float* __restrict__ bqkv, ushort* __restrict__ xb,
    float* __restrict__ maskL2)
{
  __shared__ ushort T[64][72];
  const int b = blockIdx.x, tid = threadIdx.x;
  const size_t M1 = 1024 * 1024;
  if (b < 1024) {              // Wq/Wk/Wv/Wo: 256 tiles each
    const int w = b >> 8, l = b & 255;
    const int n0 = (l & 15) * 64, k0 = (l >> 4) * 64;
    const float* src = (w == 0) ? Wq : (w == 1) ? Wk : (w == 2) ? Wv : Wo;
    ushort* dst = (w < 3) ? (Wqkvt + (size_t)w * M1) : Wot;
    transpose_tile(src, dst, HS, HS, n0, k0, tid, T);
  } else if (b < 2048) {       // W1 [1024][4096] -> W1t [4096][1024]
    const int l = b - 1024;
    transpose_tile(W1, W1t, HS, FF, (l & 63) * 64, (l >> 6) * 64, tid, T);
  } else if (b < 3072) {       // W2 [4096][1024] -> W2t [1024][4096]
    const int l = b - 2048;
    transpose_tile(W2, W2t, FF, HS, (l & 15) * 64, (l >> 4) * 64, tid, T);
  } else if (b < 5120) {       // x -> bf16, 2048 elems per block
    const size_t base = (size_t)(b - 3072) * 2048 + tid * 8;
    const float4 v0 = *(const float4*)&x[base];
    const float4 v1 = *(const float4*)&x[base + 4];
    ushort4 o0, o1;
    o0.x = f2bf(v0.x); o0.y = f2bf(v0.y); o0.z = f2bf(v0.z); o0.w = f2bf(v0.w);
    o1.x = f2bf(v1.x); o1.y = f2bf(v1.y); o1.z = f2bf(v1.z); o1.w = f2bf(v1.w);
    *(ushort4*)&xb[base] = o0;
    *(ushort4*)&xb[base + 4] = o1;
  } else {                     // bias concat + mask*log2e
#pragma unroll
    for (int t = 0; t < 12; ++t) {
      const int i = t * 256 + tid;
      bqkv[i] = (i < HS) ? bq[i] : (i < 2 * HS) ? bk[i - HS] : bv[i - 2 * HS];
    }
#pragma unroll
    for (int t = 0; t < 16; ++t) {
      const int i = t * 256 + tid;   // BSZ*SEQ = 4096 mask entries
      maskL2[i] = mask[i] * 1.44269504f;
    }
  }
}

// ======================================================================
// MFMA flash attention.  Round-11: KB=256 (8 rounds), processed as
// FOUR sequential 64-key quarter-tiles (QK->SM->PV per quarter) so live
// score state stays as[4][2] (round-5's KB=256 spill avoided).  dbuf-2
// LDS (2 x (K 32K + VT 32K)) + mask 8K = 136 KB, 1 block/CU.
// Sync per round: vmcnt(0) [only own tile outstanding — exact drain] ->
// barrier -> stage(kb+1) into the buffer the barrier just freed ->
// compute 4 quarters.  8 barriers total (was 16).
// qt=256, 512 thr = 8 waves x 32 q, grid 256 (8qt x 16h x 2b).
// Staging lane math: K 8-lane/row (verified r2-10), VT 32-lane/row with
// (sc2&24)|XOR chunk swizzle (verified round-5).
// Ones-row MFMA denominator (round-8); in-register P (T12).
// ======================================================================
__global__ __launch_bounds__(512, 2) void attention_mfma_kernel(
    const ushort* __restrict__ Qb, const ushort* __restrict__ Kb,
    const ushort* __restrict__ VTg, const float* __restrict__ maskL2,
    ushort* __restrict__ O)
{
  __shared__ ushort smem[69632];          // 136 KB
  float* mL = (float*)(smem + 65536);     // [2048] f32 maskL2 row

  const int tid = threadIdx.x;
  const int wv = tid >> 6, ln = tid & 63;
  const int c = ln & 15, g = ln >> 4;

  const unsigned d0 = blockIdx.x + 8u * (blockIdx.y + 16u * blockIdx.z);
  const unsigned w0 = (d0 & 7) * 32 + (d0 >> 3);
  const int qt = w0 & 7;
  const int hh = (w0 >> 3) & 15;
  const int b  = w0 >> 7;

  const int bh = b * NH + hh;
  const size_t row0 = (size_t)b * SEQ + (size_t)qt * 256;
  const int ch = hh * HD;
  const int wq0 = wv * 32;

  bf16x8 qf[2][2];
#pragma unroll
  for (int nt = 0; nt < 2; ++nt)
#pragma unroll
    for (int s = 0; s < 2; ++s)
      qf[nt][s] = *(const bf16x8*)&Qb[(row0 + wq0 + nt * 16 + c) * QKV_STRIDE + ch + s * 32 + g * 8];

  // stage full f32 maskL2 row for this batch (8 KB = 512 thr x 16 B).
  // Issued FIRST -> drained by the round-0 vmcnt(0).
  const float* mrow = maskL2 + (size_t)b * SEQ;
  async16((const ushort*)(mrow + wv * 256 + ln * 4), (ushort*)(mL + wv * 256));

  const int rr = ln >> 3, cc = ln & 7;     // K staging (8 lanes/row)
  const int dsub = ln >> 5, sc2 = ln & 31; // VT staging (32 lanes/row)

  // stage K (256x128B) + V^T (64x512B) of tile kb into buffer bsel.
  // 8 loads per thread (4 K + 4 VT).
  auto stage = [&](int kb, int bsel) {
    ushort* Ks  = smem + bsel * 32768;
    ushort* VTs = Ks + 16384;
    const size_t krow0 = (size_t)b * SEQ + (size_t)kb * 256;
#pragma unroll
    for (int t = 0; t < 4; ++t) {
      const int r = wv * 32 + t * 8 + rr;
      async16(Kb + (krow0 + r) * QKV_STRIDE + ch + ((cc ^ (r & 7)) * 8),
              &Ks[(size_t)(wv * 32 + t * 8) * 64]);
    }
#pragma unroll
    for (int t = 0; t < 4; ++t) {
      const int d = wv * 8 + t * 2 + dsub;
      const int srcc = (sc2 & 24) | ((sc2 & 7) ^ (d & 7));
      async16(VTg + ((size_t)bh * 64 + d) * SEQ + kb * 256 + srcc * 8,
              &VTs[(size_t)(wv * 8 + t * 2) * 256]);
    }
  };

  f32x4 ao[4][2];
#pragma unroll
  for (int i = 0; i < 4; ++i) { ao[i][0] = (f32x4){0,0,0,0}; ao[i][1] = (f32x4){0,0,0,0}; }
  f32x4 aol[2];                           // denominator accumulators (MFMA)
  aol[0] = (f32x4){0,0,0,0}; aol[1] = (f32x4){0,0,0,0};
  const short oneb = (short)0x3F80;       // bf16 1.0
  const bf16x8 ones = (bf16x8){oneb, oneb, oneb, oneb, oneb, oneb, oneb, oneb};

  stage(0, 0);                            // prologue: tile 0 in flight

  constexpr int NT = SEQ / 256;           // 8 rounds
  for (int kb = 0; kb < NT; ++kb) {
    const int cur = kb & 1;
    // gate: own tile-kb loads landed (nothing younger outstanding).
    asm volatile("s_waitcnt vmcnt(0)" ::: "memory");
    __builtin_amdgcn_s_barrier();         // all waves' kb loads landed +
    __builtin_amdgcn_sched_barrier(0);    // all waves done compute(kb-1)
    // buffer cur^1 now free: prefetch next tile (full round to land)
    if (kb + 1 < NT) stage(kb + 1, cur ^ 1);

    ushort* Ks  = smem + cur * 32768;
    ushort* VTs = Ks + 16384;

    // ---- 4 sequential 64-key quarters: QK -> SM -> PV each ----
#pragma unroll
    for (int qd = 0; qd < 4; ++qd) {
      f32x4 as_[4][2];
#pragma unroll
      for (int i = 0; i < 4; ++i) { as_[i][0] = (f32x4){0,0,0,0}; as_[i][1] = (f32x4){0,0,0,0}; }

      // QK^T quarter: keys qd*64 + mt*16 + c
      __builtin_amdgcn_s_setprio(1);
#pragma unroll
      for (int s = 0; s < 2; ++s) {
#pragma unroll
        for (int mt = 0; mt < 4; ++mt) {
          const int key = qd * 64 + mt * 16 + c;
          const bf16x8 kf = *(const bf16x8*)&Ks[(size_t)key * 64 + (((s * 4 + g) ^ (key & 7)) * 8)];
#pragma unroll
          for (int nt = 0; nt < 2; ++nt)
            as_[mt][nt] = __builtin_amdgcn_mfma_f32_16x16x32_bf16(kf, qf[nt][s], as_[mt][nt], 0, 0, 0);
        }
      }
      __builtin_amdgcn_s_setprio(0);

      // softmax quarter: p = exp2(s*(0.125*log2e) + m')
#pragma unroll
      for (int mt = 0; mt < 4; ++mt) {
        const float4 mk = *(const float4*)&mL[kb * 256 + qd * 64 + mt * 16 + g * 4];
        const float mka[4] = {mk.x, mk.y, mk.z, mk.w};
#pragma unroll
        for (int nt = 0; nt < 2; ++nt) {
#pragma unroll
          for (int r = 0; r < 4; ++r)
            as_[mt][nt][r] = EXP2(fmaf(as_[mt][nt][r], 0.18033688f, mka[r]));
        }
      }

      // PV quarter: global k-slots s = qd*2 + s2 (of 8)
#pragma unroll
      for (int s2 = 0; s2 < 2; ++s2) {
        const int s = qd * 2 + s2;
        bf16x8 pf[2];
#pragma unroll
        for (int nt = 0; nt < 2; ++nt) {
          const unsigned A0 = pkbf(as_[2 * s2][nt][0], as_[2 * s2][nt][1]);
          const unsigned A1 = pkbf(as_[2 * s2][nt][2], as_[2 * s2][nt][3]);
          const unsigned B0 = pkbf(as_[2 * s2 + 1][nt][0], as_[2 * s2 + 1][nt][1]);
          const unsigned B1 = pkbf(as_[2 * s2 + 1][nt][2], as_[2 * s2 + 1][nt][3]);
          auto x0 = __builtin_amdgcn_permlane32_swap(A0, B0, false, false);
          auto x1 = __builtin_amdgcn_permlane32_swap(A1, B1, false, false);
          auto y0 = __builtin_amdgcn_permlane16_swap(x0[0], x0[1], false, false);
          auto y1 = __builtin_amdgcn_permlane16_swap(x1[0], x1[1], false, false);
          union { unsigned w[4]; bf16x8 v; } u;
          u.w[0] = y0[0]; u.w[1] = y1[0]; u.w[2] = y0[1]; u.w[3] = y1[1];
          pf[nt] = u.v;
        }
        __builtin_amdgcn_s_setprio(1);
#pragma unroll
        for (int mt = 0; mt < 4; ++mt) {
          const int d = mt * 16 + c;
          const int k = s * 4 + g;
          const int vslot = (k & 24) | ((k & 7) ^ (d & 7));
          const bf16x8 vf = *(const bf16x8*)&VTs[(size_t)d * 256 + vslot * 8];
#pragma unroll
          for (int nt = 0; nt < 2; ++nt)
            ao[mt][nt] = __builtin_amdgcn_mfma_f32_16x16x32_bf16(vf, pf[nt], ao[mt][nt], 0, 0, 0);
        }
#pragma unroll
        for (int nt = 0; nt < 2; ++nt)
          aol[nt] = __builtin_amdgcn_mfma_f32_16x16x32_bf16(ones, pf[nt], aol[nt], 0, 0, 0);
        __builtin_amdgcn_s_setprio(0);
      }
    }
  }

  // epilogue: transpose O^T -> O via LDS, coalesced bf16 store
  __syncthreads();
  ushort* OL = smem;                      // [256 q][72]
#pragma unroll
  for (int nt = 0; nt < 2; ++nt) {
    const float inv = 1.f / aol[nt][0];
    const int q = wq0 + nt * 16 + c;
#pragma unroll
    for (int mt = 0; mt < 4; ++mt) {
      const int d = mt * 16 + g * 4;
      uint2 w;
      w.x = pkbf(ao[mt][nt][0] * inv, ao[mt][nt][1] * inv);
      w.y = pkbf(ao[mt][nt][2] * inv, ao[mt][nt][3] * inv);
      *(uint2*)&OL[q * 72 + d] = w;
    }
  }
  __syncthreads();
#pragma unroll
  for (int it = 0; it < 4; ++it) {
    const int unit = it * 512 + tid;      // 2048 units of 16 B
    const int q = unit >> 3, sg = unit & 7;
    const uint4 w = *(const uint4*)&OL[q * 72 + sg * 8];
    *(uint4*)&O[(row0 + q) * HS + ch + sg * 8] = w;
  }
}

// ======================================================================
// out = LayerNorm(X + P0 + P1 + P2 + bias) * g + b  (3-slab split-K
// reduce fused).  P2 may alias out (read-before-write per element).
// ======================================================================
__global__ __launch_bounds__(256) void add_ln_red3_kernel(
    const float* __restrict__ P0, const float* __restrict__ P1,
    const float* __restrict__ P2,
    const float* __restrict__ bias, const float* __restrict__ X,
    const float* __restrict__ g, const float* __restrict__ b,
    float* __restrict__ out)
{
  const int row = blockIdx.x;
  const int tid = threadIdx.x;
  const size_t base = (size_t)row * HS + tid * 4;
  const float4 p0 = *(const float4*)&P0[base];
  const float4 p1 = *(const float4*)&P1[base];
  const float4 p2 = *(const float4*)&P2[base];
  const float4 bi = *(const float4*)&bias[tid * 4];
  const float4 xv = *(const float4*)&X[base];
  float4 v;
  v.x = xv.x + p0.x + p1.x + p2.x + bi.x;
  v.y = xv.y + p0.y + p1.y + p2.y + bi.y;
  v.z = xv.z + p0.z + p1.z + p2.z + bi.z;
  v.w = xv.w + p0.w + p1.w + p2.w + bi.w;
  float s1 = v.x + v.y + v.z + v.w;
  float s2 = v.x * v.x + v.y * v.y + v.z * v.z + v.w * v.w;
#pragma unroll
  for (int off = 32; off > 0; off >>= 1) {
    s1 += __shfl_down(s1, off, 64);
    s2 += __shfl_down(s2, off, 64);
  }
  __shared__ float red[8];
  __shared__ float stat[2];
  const int wid = tid >> 6;
  if ((tid & 63) == 0) { red[wid] = s1; red[4 + wid] = s2; }
  __syncthreads();
  if (tid == 0) {
    const float t1 = red[0] + red[1] + red[2] + red[3];
    const float t2 = red[4] + red[5] + red[6] + red[7];
    const float mean = t1 * (1.f / HS);
    const float var = t2 * (1.f / HS) - mean * mean;
    stat[0] = mean;
    stat[1] = rsqrtf(var + EPS);
  }
  __syncthreads();
  const float mean = stat[0], rstd = stat[1];
  const float4 gv = *(const float4*)&g[tid * 4];
  const float4 bv = *(const float4*)&b[tid * 4];
  float4 r;
  r.x = (v.x - mean) * rstd * gv.x + bv.x;
  r.y = (v.y - mean) * rstd * gv.y + bv.y;
  r.z = (v.z - mean) * rstd * gv.z + bv.z;
  r.w = (v.w - mean) * rstd * gv.w + bv.w;
  *(float4*)&out[base] = r;
}

// ======================================================================
// out = LayerNorm(X + P_bf16) * g + b  (bias already fused in GEMM).
// ======================================================================
__global__ __launch_bounds__(256) void add_ln_bf16_kernel(
    const ushort* __restrict__ Pb, const float* __restrict__ X,
    const float* __restrict__ g, const float* __restrict__ b,
    float* __restrict__ out, ushort* __restrict__ outb)
{
  const int row = blockIdx.x;
  const int tid = threadIdx.x;
  const size_t base = (size_t)row * HS + tid * 4;
  const ushort4 pb = *(const ushort4*)&Pb[base];
  const float4 xv = *(const float4*)&X[base];
  float4 v;
  v.x = xv.x + bf2f(pb.x);
  v.y = xv.y + bf2f(pb.y);
  v.z = xv.z + bf2f(pb.z);
  v.w = xv.w + bf2f(pb.w);
  float s1 = v.x + v.y + v.z + v.w;
  float s2 = v.x * v.x + v.y * v.y + v.z * v.z + v.w * v.w;
#pragma unroll
  for (int off = 32; off > 0; off >>= 1) {
    s1 += __shfl_down(s1, off, 64);
    s2 += __shfl_down(s2, off, 64);
  }
  __shared__ float red[8];
  __shared__ float stat[2];
  const int wid = tid >> 6;
  if ((tid & 63) == 0) { red[wid] = s1; red[4 + wid] = s2; }
  __syncthreads();
  if (tid == 0) {
    const float t1 = red[0] + red[1] + red[2] + red[3];
    const float t2 = red[4] + red[5] + red[6] + red[7];
    const float mean = t1 * (1.f / HS);
    const float var = t2 * (1.f / HS) - mean * mean;
    stat[0] = mean;
    stat[1] = rsqrtf(var + EPS);
  }
  __syncthreads();
  const float mean = stat[0], rstd = stat[1];
  const float4 gv = *(const float4*)&g[tid * 4];
  const float4 bv = *(const float4*)&b[tid * 4];
  float4 r;
  r.x = (v.x - mean) * rstd * gv.x + bv.x;
  r.y = (v.y - mean) * rstd * gv.y + bv.y;
  r.z = (v.z - mean) * rstd * gv.z + bv.z;
  r.w = (v.w - mean) * rstd * gv.w + bv.w;
  *(float4*)&out[base] = r;
  ushort4 o;
  o.x = f2bf(r.x); o.y = f2bf(r.y); o.z = f2bf(r.z); o.w = f2bf(r.w);
  *(ushort4*)&outb[base] = o;
}

// ======================================================================
// Orchestration. Arena (ushort units, M1 = 1M ush = 2 MB), hw 94 MB:
//  0-3M   Wqkvt  (dead after QKV)    -> ff2P0 f32 0-8M  (at FF2)
//  3-4M   Wot    (dead after Wo GEMM)
//  4-8M   W1t    (dead after FF1)
//  8-12M  W2t    [live through FF2]
//  12-13M bqkv f32 (12K) + maskL2 f32 (16K at +8192)
//  13-17M xb     (dead after QKV)   -> mhab bf16 (at Wo) -> ff1o (at FF1)
//  17-29M qkvb   (dead after attn)  -> ff1o bf16 13-29M (at FF1)
//  29-33M VTg    (dead after attn)  -> h f32 29-37M (at ln1)
//  33-37M attnb  (dead after Wo)
//  37-39M hb bf16 (dead after FF1)  -> ff2P1 f32 37-45M (at FF2)
//  45-47M spare
//  ff2P2 = d_out (free until LN2; LN2 reads it before writing out)
// ======================================================================
extern "C" void kernel_launch(void* const* d_in, const int* in_sizes, int n_in,
                              void* d_out, int out_size, void* d_ws, size_t ws_size,
                              hipStream_t stream)
{
  const float* x    = (const float*)d_in[0];
  const float* mask = (const float*)d_in[1];
  const float* Wq   = (const float*)d_in[2];  const float* bq  = (const float*)d_in[3];
  const float* Wk   = (const float*)d_in[4];  const float* bk  = (const float*)d_in[5];
  const float* Wv   = (const float*)d_in[6];  const float* bv  = (const float*)d_in[7];
  const float* Wo   = (const float*)d_in[8];  const float* bo  = (const float*)d_in[9];
  const float* W1   = (const float*)d_in[10]; const float* b1  = (const float*)d_in[11];
  const float* W2   = (const float*)d_in[12]; const float* b2  = (const float*)d_in[13];
  const float* g1   = (const float*)d_in[14]; const float* be1 = (const float*)d_in[15];
  const float* g2   = (const float*)d_in[16]; const float* be2 = (const float*)d_in[17];
  float* out = (float*)d_out;

  ushort* wsu = (ushort*)d_ws;
  const size_t M1 = 1024 * 1024;

  ushort* Wqkvt = wsu;
  ushort* Wot   = wsu + 3 * M1;
  ushort* W1t   = wsu + 4 * M1;
  ushort* W2t   = wsu + 8 * M1;
  float*  bqkv  = (float*)(wsu + 12 * M1);
  float*  maskL2= (float*)(wsu + 12 * M1 + 8192);
  ushort* xb    = wsu + 13 * M1;
  ushort* qkvb  = wsu + 17 * M1;            // [4096][3072]
  ushort* VTg   = wsu + 29 * M1;
  ushort* attnb = wsu + 33 * M1;
  ushort* mhab  = wsu + 13 * M1;            // [4096][1024] bf16 (xb dead)
  float*  h     = (float*)(wsu + 29 * M1);  // aliases VTg+attnb (dead)
  ushort* hb    = wsu + 37 * M1;
  ushort* ff1o  = wsu + 13 * M1;            // [4096][4096] (mhab dead)
  float*  ff2P0 = (float*)wsu;              // 0-8M (Wqkvt/Wot/W1t dead)
  float*  ff2P1 = (float*)(wsu + 37 * M1);  // 37-45M (hb dead after FF1)
  float*  ff2P2 = out;                      // d_out as scratch slab

  const dim3 blk(256);

  prep_kernel<<<dim3(5121), blk, 0, stream>>>(
      Wq, Wk, Wv, Wo, W1, W2, bq, bk, bv, x, mask,
      Wqkvt, Wot, W1t, W2t, bqkv, xb, maskL2);

  // QKV: 8-phase 256x256 kernel, grid 12x16 = 192 blocks.
  // V columns are written transposed to VTg (vtrans fused).
  gemm8_bf16_kernel<false, true, false><<<dim3(12, 16), dim3(512), 0, stream>>>(
      xb, Wqkvt, bqkv, qkvb, VTg, nullptr, nullptr, nullptr, MROWS, 3 * HS, HS, 0);

  attention_mfma_kernel<<<dim3(SEQ / 256, NH, BSZ), dim3(512), 0, stream>>>(
      qkvb, qkvb + HS, VTg, maskL2, attnb);

  // Wo: direct bf16 out + fused bias. 64x128 tile, 512 blocks = 2/CU.
  gemm_bf16_kernel<64, 128, false, true, false><<<dim3(8, 64), blk, 0, stream>>>(
      attnb, Wot, bo, mhab, MROWS, HS, HS, HS, 0);
  add_ln_bf16_kernel<<<dim3(MROWS), blk, 0, stream>>>(
      mhab, x, g1, be1, h, hb);

  // FF1: 8-phase 256x256 kernel, grid 16x16 = 256 blocks
  gemm8_bf16_kernel<true, false, false><<<dim3(16, 16), dim3(512), 0, stream>>>(
      hb, W1t, b1, ff1o, nullptr, nullptr, nullptr, nullptr, MROWS, FF, HS, 0);

  // FF2: 8-phase split-K=3 — kSplit = 1408 = 11*128 (z2 gets 1280);
  // grid 4x16x3 = 192 blocks; f32 partials to 3 slabs (P2 = out).
  gemm8_bf16_kernel<false, false, true><<<dim3(4, 16, 3), dim3(512), 0, stream>>>(
      ff1o, W2t, nullptr, nullptr, nullptr, ff2P0, ff2P1, ff2P2,
      MROWS, HS, FF, 1408);
  add_ln_red3_kernel<<<dim3(MROWS), blk, 0, stream>>>(
      ff2P0, ff2P1, ff2P2, b2, h, g2, be2, out);
}

// Round 12
// 332.486 us; speedup vs baseline: 1.0162x; 1.0162x over previous
//
#include <hip/hip_runtime.h>
#include <hip/hip_bf16.h>

// ---- problem constants (fixed by the reference) ----
#define HS   1024
#define FF   4096
#define NH   16
#define HD   64
#define SEQ  2048
#define BSZ  2
#define MROWS (BSZ * SEQ)   // 4096 token rows
#define EPS  1e-5f
#define QKV_STRIDE (3 * HS) // fused qkv activation row stride

typedef float f32x4  __attribute__((ext_vector_type(4)));
typedef short bf16x8 __attribute__((ext_vector_type(8)));

#if __has_builtin(__builtin_amdgcn_exp2f)
#define EXP2(x) __builtin_amdgcn_exp2f(x)
#else
#define EXP2(x) exp2f(x)
#endif

__device__ __forceinline__ unsigned short f2bf(float x) {
  unsigned int u = __float_as_uint(x);
  u += 0x7fffu + ((u >> 16) & 1u);   // round-to-nearest-even
  return (unsigned short)(u >> 16);
}

__device__ __forceinline__ float bf2f(unsigned short u) {
  return __uint_as_float((unsigned int)u << 16);
}

// pack two floats -> packed bf16 pair (low = a, high = b)
__device__ __forceinline__ unsigned int pkbf(float a, float b) {
  union { __hip_bfloat162 h; unsigned int u; } x;
  x.h = __float22bfloat162_rn(float2{a, b});
  return x.u;
}

// async global->LDS, 16 B per lane; LDS dest = wave-uniform base + lane*16
__device__ __forceinline__ void async16(const ushort* g, ushort* lds) {
  __builtin_amdgcn_global_load_lds(
      (const __attribute__((address_space(1))) unsigned int*)g,
      (__attribute__((address_space(3))) unsigned int*)lds, 16, 0, 0);
}

#define BARSB { __builtin_amdgcn_s_barrier(); __builtin_amdgcn_sched_barrier(0); }

// ======================================================================
// 8-phase 256x256 bf16 GEMM (T2+T3+T4+T5 port), 512 thr = 8 waves
// (2M x 4N).  BK=64; one loop iter = 2 K-tiles (even->buf0, odd->buf1).
// Verified round-6: QKV+FF1 -20.7us vs m97 structure.
// VTRANS epilogue (round-8, verified): QKV's V-columns write transposed.
// PARTIAL split-K mode (round-10, verified): blockIdx.z selects K-range
// [z*kSplit, +kSplit); kSplit multiple of 128 preserves tile parity.
// ======================================================================
#define QUAD(kt, MH, NH)                                                      \
  {                                                                           \
    const ushort* As_ = &smem[(size_t)((kt) & 1) * 32768];                    \
    const ushort* Bs_ = As_ + 16384;                                          \
    bf16x8 af[4][2], bfr[2][2];                                               \
    _Pragma("unroll")                                                         \
    for (int mt = 0; mt < 4; ++mt)                                            \
      _Pragma("unroll")                                                       \
      for (int s = 0; s < 2; ++s) {                                           \
        const int m = wr * 128 + (MH) * 64 + mt * 16 + lr;                    \
        af[mt][s] = *(const bf16x8*)&As_[(size_t)m * 64 +                     \
                                         (((s * 4 + lg) ^ (m & 7)) * 8)];     \
      }                                                                       \
    _Pragma("unroll")                                                         \
    for (int nj = 0; nj < 2; ++nj)                                            \
      _Pragma("unroll")                                                       \
      for (int s = 0; s < 2; ++s) {                                           \
        const int n = wc * 64 + (NH) * 32 + nj * 16 + lr;                     \
        bfr[nj][s] = *(const bf16x8*)&Bs_[(size_t)n * 64 +                    \
                                          (((s * 4 + lg) ^ (n & 7)) * 8)];    \
      }                                                                       \
    __builtin_amdgcn_s_setprio(1);                                            \
    _Pragma("unroll")                                                         \
    for (int s = 0; s < 2; ++s)                                               \
      _Pragma("unroll")                                                       \
      for (int mt = 0; mt < 4; ++mt)                                          \
        _Pragma("unroll")                                                     \
        for (int nj = 0; nj < 2; ++nj)                                        \
          acc[(MH) * 4 + mt][(NH) * 2 + nj] =                                 \
              __builtin_amdgcn_mfma_f32_16x16x32_bf16(                        \
                  af[mt][s], bfr[nj][s], acc[(MH) * 4 + mt][(NH) * 2 + nj],   \
                  0, 0, 0);                                                   \
    __builtin_amdgcn_s_setprio(0);                                            \
  }

template <bool RELU, bool VTRANS, bool PARTIAL>
__global__ __launch_bounds__(512, 2) void gemm8_bf16_kernel(
    const ushort* __restrict__ A, const ushort* __restrict__ Bt,
    const float* __restrict__ bias, ushort* __restrict__ C,
    ushort* __restrict__ VTg,
    float* __restrict__ P0, float* __restrict__ P1, float* __restrict__ P2,
    int M, int N, int K, int kSplit)
{
  __shared__ ushort smem[65536];          // 128 KB
  const int tid = threadIdx.x;
  const int wv = tid >> 6, ln = tid & 63;
  const int wr = wv >> 2, wc = wv & 3;
  const int lr = ln & 15, lg = ln >> 4;
  const int rr = ln >> 3, cc = ln & 7;

  const unsigned nxy = gridDim.x * gridDim.y;
  unsigned id = blockIdx.y * gridDim.x + blockIdx.x;
  id = (id & 7) * (nxy >> 3) + (id >> 3);
  const int bn = id % gridDim.x, bm = id / gridDim.x;

  int kBeg = 0, kEnd = K;
  if (PARTIAL) {
    kBeg = blockIdx.z * kSplit;
    kEnd = kBeg + kSplit; if (kEnd > K) kEnd = K;
  }
  const int jBeg = kBeg >> 7, jEnd = kEnd >> 7;

  f32x4 acc[8][4];
#pragma unroll
  for (int i = 0; i < 8; ++i)
#pragma unroll
    for (int j = 0; j < 4; ++j) acc[i][j] = (f32x4){0.f, 0.f, 0.f, 0.f};

  // stage A-half h of tile kt: calls tt = h, h+2 (rows [tt*64, +64))
  auto stA = [&](int kt, int h) {
#pragma unroll
    for (int u = 0; u < 2; ++u) {
      const int tt = h + u * 2;
      const int R = tt * 64 + wv * 8 + rr;
      async16(A + (size_t)(bm * 256 + R) * K + kt * 64 + ((cc ^ (R & 7)) * 8),
              &smem[(size_t)(kt & 1) * 32768 + (size_t)(tt * 64 + wv * 8) * 64]);
    }
  };
  // stage B-half h of tile kt: calls tt = 2h, 2h+1 (rows [h*128, +128))
  auto stB = [&](int kt, int h) {
#pragma unroll
    for (int u = 0; u < 2; ++u) {
      const int tt = h * 2 + u;
      const int R = tt * 64 + wv * 8 + rr;
      async16(Bt + (size_t)(bn * 256 + R) * K + kt * 64 + ((cc ^ (R & 7)) * 8),
              &smem[(size_t)(kt & 1) * 32768 + 16384 + (size_t)(tt * 64 + wv * 8) * 64]);
    }
  };

  // prologue: first tile full + second tile A02 (10 loads/thread).
  const int tP = 2 * jBeg;
  stA(tP, 0); stA(tP, 1); stB(tP, 0); stB(tP, 1); stA(tP + 1, 0);

  for (int j = jBeg; j < jEnd; ++j) {
    const int t0 = 2 * j, t1 = t0 + 1;
    const bool nx = (j + 1 < jEnd);
    // ph0: gate for tile t0 reads
    BARSB;
    stA(t1, 1);
    asm volatile("s_waitcnt vmcnt(4)" ::: "memory");
    BARSB;
    QUAD(t0, 0, 0);
    // ph1
    BARSB; stB(t1, 0); QUAD(t0, 0, 1);
    // ph2 (A02 of buf0 dead after ph1)
    BARSB; if (nx) stA(t0 + 2, 0); QUAD(t0, 1, 0);
    // ph3
    BARSB; stB(t1, 1); QUAD(t0, 1, 1);
    // ph4: gate for tile t1 reads
    BARSB;
    if (nx) {
      stA(t0 + 2, 1);
      asm volatile("s_waitcnt vmcnt(2)" ::: "memory");
    } else {
      asm volatile("s_waitcnt vmcnt(0)" ::: "memory");
    }
    BARSB;
    QUAD(t1, 0, 0);
    // ph5
    BARSB; if (nx) stB(t0 + 2, 0); QUAD(t1, 0, 1);
    // ph6
    BARSB; if (nx) stB(t0 + 2, 1); QUAD(t1, 1, 0);
    // ph7 (A02 of buf1 dead after ph5)
    BARSB; if (nx) stA(t0 + 3, 0); QUAD(t1, 1, 1);
  }

  const int gm0 = bm * 256 + wr * 128;
  const int gn0 = bn * 256 + wc * 64;

  if (PARTIAL) {
    float* Cp = (blockIdx.z == 0) ? P0 : (blockIdx.z == 1) ? P1 : P2;
#pragma unroll
    for (int i = 0; i < 8; ++i) {
#pragma unroll
      for (int r = 0; r < 4; ++r) {
        const size_t row = (size_t)(gm0 + i * 16 + lg * 4 + r);
#pragma unroll
        for (int j = 0; j < 4; ++j)
          Cp[row * N + gn0 + j * 16 + lr] = acc[i][j][r];
      }
    }
    return;
  }

  // epilogue: bias + (relu) + bf16 store
  float bs4[4];
#pragma unroll
  for (int j = 0; j < 4; ++j) bs4[j] = bias[gn0 + j * 16 + lr];

  if (VTRANS && gn0 >= 2 * HS) {
    // V columns: write transposed to VTg[(b*16+h)*64+d][seq].
#pragma unroll
    for (int i = 0; i < 8; ++i) {
#pragma unroll
      for (int j = 0; j < 4; ++j) {
        const int col = gn0 - 2 * HS + j * 16 + lr;   // h*64 + d
        const int rowb = gm0 + i * 16 + lg * 4;
        const int bb = rowb >> 11;                    // batch
        const int seq = rowb & (SEQ - 1);
        ushort4 o;
        o.x = f2bf(acc[i][j][0] + bs4[j]);
        o.y = f2bf(acc[i][j][1] + bs4[j]);
        o.z = f2bf(acc[i][j][2] + bs4[j]);
        o.w = f2bf(acc[i][j][3] + bs4[j]);
        *(ushort4*)&VTg[((size_t)(bb * NH + (col >> 6)) * 64 + (col & 63)) * SEQ + seq] = o;
      }
    }
  } else {
#pragma unroll
    for (int i = 0; i < 8; ++i) {
#pragma unroll
      for (int r = 0; r < 4; ++r) {
        const size_t row = (size_t)(gm0 + i * 16 + lg * 4 + r);
#pragma unroll
        for (int j = 0; j < 4; ++j) {
          float val = acc[i][j][r] + bs4[j];
          if (RELU) val = fmaxf(val, 0.f);
          C[row * N + gn0 + j * 16 + lr] = f2bf(val);
        }
      }
    }
  }
}

// ======================================================================
// bf16 MFMA GEMM (m97 structure): C = A@B + bias, Bt = B^T [N][K].
// Used for Wo (64x128, 512 blocks = 2/CU).
// ======================================================================
template <int TBM, int TBN, bool RELU, bool OUT_BF16, bool PARTIAL>
__global__ __launch_bounds__(256) void gemm_bf16_kernel(
    const ushort* __restrict__ A, const ushort* __restrict__ Bt,
    const float* __restrict__ bias, void* __restrict__ Cout,
    int M, int N, int K, int kLen, size_t zstride)
{
  constexpr int MI = TBM / 32;
  constexpr int NJ = TBN / 32;
  __shared__ ushort As[TBM * 64];
  __shared__ ushort Bs[TBN * 64];

  const int tid = threadIdx.x;
  const int wv = tid >> 6, ln = tid & 63;

  const unsigned nxy = gridDim.x * gridDim.y;
  unsigned id = blockIdx.y * gridDim.x + blockIdx.x;
  id = (id & 7) * (nxy >> 3) + (id >> 3);
  const int bn = id % gridDim.x, bm = id / gridDim.x;

  const int lr = ln & 15;
  const int lg = ln >> 4;
  const int mrow_base = (wv >> 1) * (TBM / 2);
  const int ncol_base = (wv & 1) * (TBN / 2);

  f32x4 acc[MI][NJ];
#pragma unroll
  for (int i = 0; i < MI; ++i)
#pragma unroll
    for (int j = 0; j < NJ; ++j) acc[i][j] = (f32x4){0.f, 0.f, 0.f, 0.f};

  const int rr = ln >> 3, cc = ln & 7;
  const int kBeg = blockIdx.z * kLen, kEnd = kBeg + kLen;

  for (int k0 = kBeg; k0 < kEnd; k0 += 64) {
    __syncthreads();
#pragma unroll
    for (int t = 0; t < TBM / 32; ++t) {
      const int R = wv * (TBM / 4) + t * 8 + rr;
      const int c = cc ^ (R & 7);
      async16(A + (size_t)(bm * TBM + R) * K + k0 + c * 8,
              &As[(size_t)(wv * (TBM / 4) + t * 8) * 64]);
    }
#pragma unroll
    for (int t = 0; t < TBN / 32; ++t) {
      const int R = wv * (TBN / 4) + t * 8 + rr;
      const int c = cc ^ (R & 7);
      async16(Bt + (size_t)(bn * TBN + R) * K + k0 + c * 8,
              &Bs[(size_t)(wv * (TBN / 4) + t * 8) * 64]);
    }
    __syncthreads();

#pragma unroll
    for (int s = 0; s < 2; ++s) {
      bf16x8 a[MI], b[NJ];
#pragma unroll
      for (int i = 0; i < MI; ++i) {
        const int m = mrow_base + i * 16 + lr;
        a[i] = *(const bf16x8*)&As[(size_t)m * 64 + (((s * 4 + lg) ^ (m & 7)) * 8)];
      }
#pragma unroll
      for (int j = 0; j < NJ; ++j) {
        const int n = ncol_base + j * 16 + lr;
        b[j] = *(const bf16x8*)&Bs[(size_t)n * 64 + (((s * 4 + lg) ^ (n & 7)) * 8)];
      }
#pragma unroll
      for (int i = 0; i < MI; ++i)
#pragma unroll
        for (int j = 0; j < NJ; ++j)
          acc[i][j] = __builtin_amdgcn_mfma_f32_16x16x32_bf16(a[i], b[j], acc[i][j], 0, 0, 0);
    }
  }

  const int gm0 = bm * TBM + mrow_base;
  const int gn0 = bn * TBN + ncol_base;

  if (PARTIAL) {
    float* Cp = (float*)Cout + (size_t)blockIdx.z * zstride;
#pragma unroll
    for (int i = 0; i < MI; ++i)
#pragma unroll
      for (int r = 0; r < 4; ++r) {
        const size_t row = (size_t)(gm0 + i * 16 + lg * 4 + r);
#pragma unroll
        for (int j = 0; j < NJ; ++j)
          Cp[row * N + gn0 + j * 16 + lr] = acc[i][j][r];
      }
  } else {
    float bs4[NJ];
#pragma unroll
    for (int j = 0; j < NJ; ++j) bs4[j] = bias[gn0 + j * 16 + lr];
    float* Cf = (float*)Cout;
    ushort* Cb = (ushort*)Cout;
#pragma unroll
    for (int i = 0; i < MI; ++i) {
#pragma unroll
      for (int r = 0; r < 4; ++r) {
        const size_t row = (size_t)(gm0 + i * 16 + lg * 4 + r);
#pragma unroll
        for (int j = 0; j < NJ; ++j) {
          float val = acc[i][j][r] + bs4[j];
          if (RELU) val = fmaxf(val, 0.f);
          const size_t idx = row * N + gn0 + j * 16 + lr;
          if (OUT_BF16) Cb[idx] = f2bf(val);
          else          Cf[idx] = val;
        }
      }
    }
  }
}

// ======================================================================
// Fused prep kernel: 6 weight transposes (fp32 [K][N] -> bf16 [N][K]),
// bias concat, x -> bf16, mask*log2e (f32, for exp2 softmax).
// ======================================================================
__device__ __forceinline__ void transpose_tile(
    const float* __restrict__ W, ushort* __restrict__ Wt,
    int K, int N, int n0, int k0, int tid, ushort (*T)[72])
{
#pragma unroll
  for (int t = 0; t < 4; ++t) {
    const int r = t * 16 + (tid >> 4);
    const int c = (tid & 15) * 4;
    const float4 w = *(const float4*)&W[(size_t)(k0 + r) * N + n0 + c];
    T[c + 0][r] = f2bf(w.x); T[c + 1][r] = f2bf(w.y);
    T[c + 2][r] = f2bf(w.z); T[c + 3][r] = f2bf(w.w);
  }
  __syncthreads();
#pragma unroll
  for (int t = 0; t < 4; ++t) {
    const int n = t * 16 + (tid >> 4);
    const int kc = (tid & 15) * 4;
    ushort4 o;
    o.x = T[n][kc]; o.y = T[n][kc + 1]; o.z = T[n][kc + 2]; o.w = T[n][kc + 3];
    *(ushort4*)&Wt[(size_t)(n0 + n) * K + k0 + kc] = o;
  }
}

__global__ __launch_bounds__(256) void prep_kernel(
    const float* __restrict__ Wq, const float* __restrict__ Wk,
    const float* __restrict__ Wv, const float* __restrict__ Wo,
    const float* __restrict__ W1, const float* __restrict__ W2,
    const float* __restrict__ bq, const float* __restrict__ bk,
    const float* __restrict__ bv, const float* __restrict__ x,
    const float* __restrict__ mask,
    ushort* __restrict__ Wqkvt, ushort* __restrict__ Wot,
    ushort* __restrict__ W1t, ushort* __restrict__ W2t,
    float* __restrict__ bqkv, ushort* __restrict__ xb,
    float* __restrict__ maskL2)
{
  __shared__ ushort T[64][72];
  const int b = blockIdx.x, tid = threadIdx.x;
  const size_t M1 = 1024 * 1024;
  if (b < 1024) {              // Wq/Wk/Wv/Wo: 256 tiles each
    const int w = b >> 8, l = b & 255;
    const int n0 = (l & 15) * 64, k0 = (l >> 4) * 64;
    const float* src = (w == 0) ? Wq : (w == 1) ? Wk : (w == 2) ? Wv : Wo;
    ushort* dst = (w < 3) ? (Wqkvt + (size_t)w * M1) : Wot;
    transpose_tile(src, dst, HS, HS, n0, k0, tid, T);
  } else if (b < 2048) {       // W1 [1024][4096] -> W1t [4096][1024]
    const int l = b - 1024;
    transpose_tile(W1, W1t, HS, FF, (l & 63) * 64, (l >> 6) * 64, tid, T);
  } else if (b < 3072) {       // W2 [4096][1024] -> W2t [1024][4096]
    const int l = b - 2048;
    transpose_tile(W2, W2t, FF, HS, (l & 15) * 64, (l >> 4) * 64, tid, T);
  } else if (b < 5120) {       // x -> bf16, 2048 elems per block
    const size_t base = (size_t)(b - 3072) * 2048 + tid * 8;
    const float4 v0 = *(const float4*)&x[base];
    const float4 v1 = *(const float4*)&x[base + 4];
    ushort4 o0, o1;
    o0.x = f2bf(v0.x); o0.y = f2bf(v0.y); o0.z = f2bf(v0.z); o0.w = f2bf(v0.w);
    o1.x = f2bf(v1.x); o1.y = f2bf(v1.y); o1.z = f2bf(v1.z); o1.w = f2bf(v1.w);
    *(ushort4*)&xb[base] = o0;
    *(ushort4*)&xb[base + 4] = o1;
  } else {                     // bias concat + mask*log2e
#pragma unroll
    for (int t = 0; t < 12; ++t) {
      const int i = t * 256 + tid;
      bqkv[i] = (i < HS) ? bq[i] : (i < 2 * HS) ? bk[i - HS] : bv[i - 2 * HS];
    }
#pragma unroll
    for (int t = 0; t < 16; ++t) {
      const int i = t * 256 + tid;   // BSZ*SEQ = 4096 mask entries
      maskL2[i] = mask[i] * 1.44269504f;
    }
  }
}

// ======================================================================
// MFMA flash attention (round-10 verified best, 54.0us): ring-4 LDS
// buffers, ONE barrier per KV round, 2-deep prefetch with counted
// vmcnt(8) (never 0 in steady state).  KB=128 (16 rounds), qt=256,
// 512 thr = 8 waves x 32 q, grid 256 = 1 block/CU.  LDS 136 KB.
// Half-tile pipelined (round-9), ones-row MFMA denominator (round-8),
// in-register P via cvt_pk + permlane32/16_swap (T12).
// ======================================================================
__global__ __launch_bounds__(512, 2) void attention_mfma_kernel(
    const ushort* __restrict__ Qb, const ushort* __restrict__ Kb,
    const ushort* __restrict__ VTg, const float* __restrict__ maskL2,
    ushort* __restrict__ O)
{
  __shared__ ushort smem[69632];          // 136 KB
  float* mL = (float*)(smem + 65536);     // [2048] f32 maskL2 row

  const int tid = threadIdx.x;
  const int wv = tid >> 6, ln = tid & 63;
  const int c = ln & 15, g = ln >> 4;

  const unsigned d0 = blockIdx.x + 8u * (blockIdx.y + 16u * blockIdx.z);
  const unsigned w0 = (d0 & 7) * 32 + (d0 >> 3);
  const int qt = w0 & 7;
  const int hh = (w0 >> 3) & 15;
  const int b  = w0 >> 7;

  const int bh = b * NH + hh;
  const size_t row0 = (size_t)b * SEQ + (size_t)qt * 256;
  const int ch = hh * HD;
  const int wq0 = wv * 32;

  bf16x8 qf[2][2];
#pragma unroll
  for (int nt = 0; nt < 2; ++nt)
#pragma unroll
    for (int s = 0; s < 2; ++s)
      qf[nt][s] = *(const bf16x8*)&Qb[(row0 + wq0 + nt * 16 + c) * QKV_STRIDE + ch + s * 32 + g * 8];

  // stage full f32 maskL2 row for this batch (8 KB = 512 thr x 16 B).
  const float* mrow = maskL2 + (size_t)b * SEQ;
  async16((const ushort*)(mrow + wv * 256 + ln * 4), (ushort*)(mL + wv * 256));

  const int rr = ln >> 3, cc = ln & 7;    // K staging coords (8 lanes/row)
  const int r4 = ln >> 4, sc = ln & 15;   // VT staging coords (16 lanes/row)

  auto stage = [&](int kb, int bsel) {
    ushort* Ks  = smem + bsel * 16384;
    ushort* VTs = Ks + 8192;
    const size_t krow0 = (size_t)b * SEQ + (size_t)kb * 128;
#pragma unroll
    for (int t = 0; t < 2; ++t) {
      const int r = wv * 16 + t * 8 + rr;
      async16(Kb + (krow0 + r) * QKV_STRIDE + ch + ((cc ^ (r & 7)) * 8),
              &Ks[(size_t)(wv * 16 + t * 8) * 64]);
    }
#pragma unroll
    for (int t = 0; t < 2; ++t) {
      const int d = wv * 8 + t * 4 + r4;
      const int srcc = (sc & 8) | ((sc & 7) ^ (d & 7));
      async16(VTg + ((size_t)bh * 64 + d) * SEQ + kb * 128 + srcc * 8,
              &VTs[(size_t)(wv * 8 + t * 4) * 128]);
    }
  };

  f32x4 ao[4][2];
#pragma unroll
  for (int i = 0; i < 4; ++i) { ao[i][0] = (f32x4){0,0,0,0}; ao[i][1] = (f32x4){0,0,0,0}; }
  f32x4 aol[2];                           // denominator accumulators (MFMA)
  aol[0] = (f32x4){0,0,0,0}; aol[1] = (f32x4){0,0,0,0};
  const short oneb = (short)0x3F80;       // bf16 1.0
  const bf16x8 ones = (bf16x8){oneb, oneb, oneb, oneb, oneb, oneb, oneb, oneb};

  stage(0, 0);                            // prologue: tiles 0,1 in flight
  stage(1, 1);

  constexpr int NT = SEQ / 128;           // 16 rounds
  for (int kb = 0; kb < NT; ++kb) {
    const int cur = kb & 3;
    if (kb + 2 < NT) stage(kb + 2, (kb + 2) & 3);
    if (kb + 2 < NT)      asm volatile("s_waitcnt vmcnt(8)" ::: "memory");
    else if (kb + 1 < NT) asm volatile("s_waitcnt vmcnt(4)" ::: "memory");
    else                  asm volatile("s_waitcnt vmcnt(0)" ::: "memory");
    __builtin_amdgcn_s_barrier();
    __builtin_amdgcn_sched_barrier(0);

    ushort* Ks  = smem + cur * 16384;
    ushort* VTs = Ks + 8192;

    // ---- S^T = K @ Q^T, two halves: A = keys 0-63, B = keys 64-127 ----
    f32x4 asA[4][2], asB[4][2];
#pragma unroll
    for (int i = 0; i < 4; ++i) {
      asA[i][0] = (f32x4){0,0,0,0}; asA[i][1] = (f32x4){0,0,0,0};
      asB[i][0] = (f32x4){0,0,0,0}; asB[i][1] = (f32x4){0,0,0,0};
    }
    __builtin_amdgcn_s_setprio(1);
#pragma unroll
    for (int s = 0; s < 2; ++s) {
#pragma unroll
      for (int mt = 0; mt < 4; ++mt) {
        const int key = mt * 16 + c;
        const bf16x8 kf = *(const bf16x8*)&Ks[(size_t)key * 64 + (((s * 4 + g) ^ (key & 7)) * 8)];
#pragma unroll
        for (int nt = 0; nt < 2; ++nt)
          asA[mt][nt] = __builtin_amdgcn_mfma_f32_16x16x32_bf16(kf, qf[nt][s], asA[mt][nt], 0, 0, 0);
      }
    }
#pragma unroll
    for (int s = 0; s < 2; ++s) {
#pragma unroll
      for (int mt = 0; mt < 4; ++mt) {
        const int key = (mt + 4) * 16 + c;
        const bf16x8 kf = *(const bf16x8*)&Ks[(size_t)key * 64 + (((s * 4 + g) ^ (key & 7)) * 8)];
#pragma unroll
        for (int nt = 0; nt < 2; ++nt)
          asB[mt][nt] = __builtin_amdgcn_mfma_f32_16x16x32_bf16(kf, qf[nt][s], asB[mt][nt], 0, 0, 0);
      }
    }
    __builtin_amdgcn_s_setprio(0);

    // ---- softmax half A (overlaps QK^T(B) MFMA drain) ----
#pragma unroll
    for (int mt = 0; mt < 4; ++mt) {
      const float4 mk = *(const float4*)&mL[kb * 128 + mt * 16 + g * 4];
      const float mka[4] = {mk.x, mk.y, mk.z, mk.w};
#pragma unroll
      for (int nt = 0; nt < 2; ++nt) {
#pragma unroll
        for (int r = 0; r < 4; ++r)
          asA[mt][nt][r] = EXP2(fmaf(asA[mt][nt][r], 0.18033688f, mka[r]));
      }
    }

    // ---- PV slots s=0,1 (half A) ----
#pragma unroll
    for (int s = 0; s < 2; ++s) {
      bf16x8 pf[2];
#pragma unroll
      for (int nt = 0; nt < 2; ++nt) {
        const unsigned A0 = pkbf(asA[2 * s][nt][0], asA[2 * s][nt][1]);
        const unsigned A1 = pkbf(asA[2 * s][nt][2], asA[2 * s][nt][3]);
        const unsigned B0 = pkbf(asA[2 * s + 1][nt][0], asA[2 * s + 1][nt][1]);
        const unsigned B1 = pkbf(asA[2 * s + 1][nt][2], asA[2 * s + 1][nt][3]);
        auto x0 = __builtin_amdgcn_permlane32_swap(A0, B0, false, false);
        auto x1 = __builtin_amdgcn_permlane32_swap(A1, B1, false, false);
        auto y0 = __builtin_amdgcn_permlane16_swap(x0[0], x0[1], false, false);
        auto y1 = __builtin_amdgcn_permlane16_swap(x1[0], x1[1], false, false);
        union { unsigned w[4]; bf16x8 v; } u;
        u.w[0] = y0[0]; u.w[1] = y1[0]; u.w[2] = y0[1]; u.w[3] = y1[1];
        pf[nt] = u.v;
      }
      __builtin_amdgcn_s_setprio(1);
#pragma unroll
      for (int mt = 0; mt < 4; ++mt) {
        const int d = mt * 16 + c;
        const int k = s * 4 + g;
        const int vslot = (k & 8) | ((k & 7) ^ (d & 7));
        const bf16x8 vf = *(const bf16x8*)&VTs[(size_t)d * 128 + vslot * 8];
#pragma unroll
        for (int nt = 0; nt < 2; ++nt)
          ao[mt][nt] = __builtin_amdgcn_mfma_f32_16x16x32_bf16(vf, pf[nt], ao[mt][nt], 0, 0, 0);
      }
#pragma unroll
      for (int nt = 0; nt < 2; ++nt)
        aol[nt] = __builtin_amdgcn_mfma_f32_16x16x32_bf16(ones, pf[nt], aol[nt], 0, 0, 0);
      __builtin_amdgcn_s_setprio(0);
    }

    // ---- softmax half B ----
#pragma unroll
    for (int mt = 0; mt < 4; ++mt) {
      const float4 mk = *(const float4*)&mL[kb * 128 + (mt + 4) * 16 + g * 4];
      const float mka[4] = {mk.x, mk.y, mk.z, mk.w};
#pragma unroll
      for (int nt = 0; nt < 2; ++nt) {
#pragma unroll
        for (int r = 0; r < 4; ++r)
          asB[mt][nt][r] = EXP2(fmaf(asB[mt][nt][r], 0.18033688f, mka[r]));
      }
    }

    // ---- PV slots s=2,3 (half B) ----
#pragma unroll
    for (int s = 2; s < 4; ++s) {
      const int sb = s - 2;
      bf16x8 pf[2];
#pragma unroll
      for (int nt = 0; nt < 2; ++nt) {
        const unsigned A0 = pkbf(asB[2 * sb][nt][0], asB[2 * sb][nt][1]);
        const unsigned A1 = pkbf(asB[2 * sb][nt][2], asB[2 * sb][nt][3]);
        const unsigned B0 = pkbf(asB[2 * sb + 1][nt][0], asB[2 * sb + 1][nt][1]);
        const unsigned B1 = pkbf(asB[2 * sb + 1][nt][2], asB[2 * sb + 1][nt][3]);
        auto x0 = __builtin_amdgcn_permlane32_swap(A0, B0, false, false);
        auto x1 = __builtin_amdgcn_permlane32_swap(A1, B1, false, false);
        auto y0 = __builtin_amdgcn_permlane16_swap(x0[0], x0[1], false, false);
        auto y1 = __builtin_amdgcn_permlane16_swap(x1[0], x1[1], false, false);
        union { unsigned w[4]; bf16x8 v; } u;
        u.w[0] = y0[0]; u.w[1] = y1[0]; u.w[2] = y0[1]; u.w[3] = y1[1];
        pf[nt] = u.v;
      }
      __builtin_amdgcn_s_setprio(1);
#pragma unroll
      for (int mt = 0; mt < 4; ++mt) {
        const int d = mt * 16 + c;
        const int k = s * 4 + g;
        const int vslot = (k & 8) | ((k & 7) ^ (d & 7));
        const bf16x8 vf = *(const bf16x8*)&VTs[(size_t)d * 128 + vslot * 8];
#pragma unroll
        for (int nt = 0; nt < 2; ++nt)
          ao[mt][nt] = __builtin_amdgcn_mfma_f32_16x16x32_bf16(vf, pf[nt], ao[mt][nt], 0, 0, 0);
      }
#pragma unroll
      for (int nt = 0; nt < 2; ++nt)
        aol[nt] = __builtin_amdgcn_mfma_f32_16x16x32_bf16(ones, pf[nt], aol[nt], 0, 0, 0);
      __builtin_amdgcn_s_setprio(0);
    }
  }

  // epilogue: transpose O^T -> O via LDS, coalesced bf16 store
  __syncthreads();
  ushort* OL = smem;                      // [256 q][72]
#pragma unroll
  for (int nt = 0; nt < 2; ++nt) {
    const float inv = 1.f / aol[nt][0];
    const int q = wq0 + nt * 16 + c;
#pragma unroll
    for (int mt = 0; mt < 4; ++mt) {
      const int d = mt * 16 + g * 4;
      uint2 w;
      w.x = pkbf(ao[mt][nt][0] * inv, ao[mt][nt][1] * inv);
      w.y = pkbf(ao[mt][nt][2] * inv, ao[mt][nt][3] * inv);
      *(uint2*)&OL[q * 72 + d] = w;
    }
  }
  __syncthreads();
#pragma unroll
  for (int it = 0; it < 4; ++it) {
    const int unit = it * 512 + tid;      // 2048 units of 16 B
    const int q = unit >> 3, sg = unit & 7;
    const uint4 w = *(const uint4*)&OL[q * 72 + sg * 8];
    *(uint4*)&O[(row0 + q) * HS + ch + sg * 8] = w;
  }
}

// ======================================================================
// out = LayerNorm(X + P0 + P1 + P2 + bias) * g + b  (3-slab split-K
// reduce fused).  P2 may alias out (read-before-write per element).
// ======================================================================
__global__ __launch_bounds__(256) void add_ln_red3_kernel(
    const float* __restrict__ P0, const float* __restrict__ P1,
    const float* __restrict__ P2,
    const float* __restrict__ bias, const float* __restrict__ X,
    const float* __restrict__ g, const float* __restrict__ b,
    float* __restrict__ out)
{
  const int row = blockIdx.x;
  const int tid = threadIdx.x;
  const size_t base = (size_t)row * HS + tid * 4;
  const float4 p0 = *(const float4*)&P0[base];
  const float4 p1 = *(const float4*)&P1[base];
  const float4 p2 = *(const float4*)&P2[base];
  const float4 bi = *(const float4*)&bias[tid * 4];
  const float4 xv = *(const float4*)&X[base];
  float4 v;
  v.x = xv.x + p0.x + p1.x + p2.x + bi.x;
  v.y = xv.y + p0.y + p1.y + p2.y + bi.y;
  v.z = xv.z + p0.z + p1.z + p2.z + bi.z;
  v.w = xv.w + p0.w + p1.w + p2.w + bi.w;
  float s1 = v.x + v.y + v.z + v.w;
  float s2 = v.x * v.x + v.y * v.y + v.z * v.z + v.w * v.w;
#pragma unroll
  for (int off = 32; off > 0; off >>= 1) {
    s1 += __shfl_down(s1, off, 64);
    s2 += __shfl_down(s2, off, 64);
  }
  __shared__ float red[8];
  __shared__ float stat[2];
  const int wid = tid >> 6;
  if ((tid & 63) == 0) { red[wid] = s1; red[4 + wid] = s2; }
  __syncthreads();
  if (tid == 0) {
    const float t1 = red[0] + red[1] + red[2] + red[3];
    const float t2 = red[4] + red[5] + red[6] + red[7];
    const float mean = t1 * (1.f / HS);
    const float var = t2 * (1.f / HS) - mean * mean;
    stat[0] = mean;
    stat[1] = rsqrtf(var + EPS);
  }
  __syncthreads();
  const float mean = stat[0], rstd = stat[1];
  const float4 gv = *(const float4*)&g[tid * 4];
  const float4 bv = *(const float4*)&b[tid * 4];
  float4 r;
  r.x = (v.x - mean) * rstd * gv.x + bv.x;
  r.y = (v.y - mean) * rstd * gv.y + bv.y;
  r.z = (v.z - mean) * rstd * gv.z + bv.z;
  r.w = (v.w - mean) * rstd * gv.w + bv.w;
  *(float4*)&out[base] = r;
}

// ======================================================================
// out = LayerNorm(X + P_bf16) * g + b  (bias already fused in GEMM).
// ======================================================================
__global__ __launch_bounds__(256) void add_ln_bf16_kernel(
    const ushort* __restrict__ Pb, const float* __restrict__ X,
    const float* __restrict__ g, const float* __restrict__ b,
    float* __restrict__ out, ushort* __restrict__ outb)
{
  const int row = blockIdx.x;
  const int tid = threadIdx.x;
  const size_t base = (size_t)row * HS + tid * 4;
  const ushort4 pb = *(const ushort4*)&Pb[base];
  const float4 xv = *(const float4*)&X[base];
  float4 v;
  v.x = xv.x + bf2f(pb.x);
  v.y = xv.y + bf2f(pb.y);
  v.z = xv.z + bf2f(pb.z);
  v.w = xv.w + bf2f(pb.w);
  float s1 = v.x + v.y + v.z + v.w;
  float s2 = v.x * v.x + v.y * v.y + v.z * v.z + v.w * v.w;
#pragma unroll
  for (int off = 32; off > 0; off >>= 1) {
    s1 += __shfl_down(s1, off, 64);
    s2 += __shfl_down(s2, off, 64);
  }
  __shared__ float red[8];
  __shared__ float stat[2];
  const int wid = tid >> 6;
  if ((tid & 63) == 0) { red[wid] = s1; red[4 + wid] = s2; }
  __syncthreads();
  if (tid == 0) {
    const float t1 = red[0] + red[1] + red[2] + red[3];
    const float t2 = red[4] + red[5] + red[6] + red[7];
    const float mean = t1 * (1.f / HS);
    const float var = t2 * (1.f / HS) - mean * mean;
    stat[0] = mean;
    stat[1] = rsqrtf(var + EPS);
  }
  __syncthreads();
  const float mean = stat[0], rstd = stat[1];
  const float4 gv = *(const float4*)&g[tid * 4];
  const float4 bv = *(const float4*)&b[tid * 4];
  float4 r;
  r.x = (v.x - mean) * rstd * gv.x + bv.x;
  r.y = (v.y - mean) * rstd * gv.y + bv.y;
  r.z = (v.z - mean) * rstd * gv.z + bv.z;
  r.w = (v.w - mean) * rstd * gv.w + bv.w;
  *(float4*)&out[base] = r;
  ushort4 o;
  o.x = f2bf(r.x); o.y = f2bf(r.y); o.z = f2bf(r.z); o.w = f2bf(r.w);
  *(ushort4*)&outb[base] = o;
}

// ======================================================================
// Orchestration. Arena (ushort units, M1 = 1M ush = 2 MB), hw 94 MB:
//  0-3M   Wqkvt  (dead after QKV)    -> ff2P0 f32 0-8M  (at FF2)
//  3-4M   Wot    (dead after Wo GEMM)
//  4-8M   W1t    (dead after FF1)
//  8-12M  W2t    [live through FF2]
//  12-13M bqkv f32 (12K) + maskL2 f32 (16K at +8192)
//  13-17M xb     (dead after QKV)   -> mhab bf16 (at Wo) -> ff1o (at FF1)
//  17-29M qkvb   (dead after attn)  -> ff1o bf16 13-29M (at FF1)
//  29-33M VTg    (dead after attn)  -> h f32 29-37M (at ln1)
//  33-37M attnb  (dead after Wo)
//  37-39M hb bf16 (dead after FF1)  -> ff2P1 f32 37-45M (at FF2)
//  45-47M spare
//  ff2P2 = d_out (free until LN2; LN2 reads it before writing out)
// ======================================================================
extern "C" void kernel_launch(void* const* d_in, const int* in_sizes, int n_in,
                              void* d_out, int out_size, void* d_ws, size_t ws_size,
                              hipStream_t stream)
{
  const float* x    = (const float*)d_in[0];
  const float* mask = (const float*)d_in[1];
  const float* Wq   = (const float*)d_in[2];  const float* bq  = (const float*)d_in[3];
  const float* Wk   = (const float*)d_in[4];  const float* bk  = (const float*)d_in[5];
  const float* Wv   = (const float*)d_in[6];  const float* bv  = (const float*)d_in[7];
  const float* Wo   = (const float*)d_in[8];  const float* bo  = (const float*)d_in[9];
  const float* W1   = (const float*)d_in[10]; const float* b1  = (const float*)d_in[11];
  const float* W2   = (const float*)d_in[12]; const float* b2  = (const float*)d_in[13];
  const float* g1   = (const float*)d_in[14]; const float* be1 = (const float*)d_in[15];
  const float* g2   = (const float*)d_in[16]; const float* be2 = (const float*)d_in[17];
  float* out = (float*)d_out;

  ushort* wsu = (ushort*)d_ws;
  const size_t M1 = 1024 * 1024;

  ushort* Wqkvt = wsu;
  ushort* Wot   = wsu + 3 * M1;
  ushort* W1t   = wsu + 4 * M1;
  ushort* W2t   = wsu + 8 * M1;
  float*  bqkv  = (float*)(wsu + 12 * M1);
  float*  maskL2= (float*)(wsu + 12 * M1 + 8192);
  ushort* xb    = wsu + 13 * M1;
  ushort* qkvb  = wsu + 17 * M1;            // [4096][3072]
  ushort* VTg   = wsu + 29 * M1;
  ushort* attnb = wsu + 33 * M1;
  ushort* mhab  = wsu + 13 * M1;            // [4096][1024] bf16 (xb dead)
  float*  h     = (float*)(wsu + 29 * M1);  // aliases VTg+attnb (dead)
  ushort* hb    = wsu + 37 * M1;
  ushort* ff1o  = wsu + 13 * M1;            // [4096][4096] (mhab dead)
  float*  ff2P0 = (float*)wsu;              // 0-8M (Wqkvt/Wot/W1t dead)
  float*  ff2P1 = (float*)(wsu + 37 * M1);  // 37-45M (hb dead after FF1)
  float*  ff2P2 = out;                      // d_out as scratch slab

  const dim3 blk(256);

  prep_kernel<<<dim3(5121), blk, 0, stream>>>(
      Wq, Wk, Wv, Wo, W1, W2, bq, bk, bv, x, mask,
      Wqkvt, Wot, W1t, W2t, bqkv, xb, maskL2);

  // QKV: 8-phase 256x256 kernel, grid 12x16 = 192 blocks.
  // V columns are written transposed to VTg (vtrans fused).
  gemm8_bf16_kernel<false, true, false><<<dim3(12, 16), dim3(512), 0, stream>>>(
      xb, Wqkvt, bqkv, qkvb, VTg, nullptr, nullptr, nullptr, MROWS, 3 * HS, HS, 0);

  attention_mfma_kernel<<<dim3(SEQ / 256, NH, BSZ), dim3(512), 0, stream>>>(
      qkvb, qkvb + HS, VTg, maskL2, attnb);

  // Wo: direct bf16 out + fused bias. 64x128 tile, 512 blocks = 2/CU.
  gemm_bf16_kernel<64, 128, false, true, false><<<dim3(8, 64), blk, 0, stream>>>(
      attnb, Wot, bo, mhab, MROWS, HS, HS, HS, 0);
  add_ln_bf16_kernel<<<dim3(MROWS), blk, 0, stream>>>(
      mhab, x, g1, be1, h, hb);

  // FF1: 8-phase 256x256 kernel, grid 16x16 = 256 blocks
  gemm8_bf16_kernel<true, false, false><<<dim3(16, 16), dim3(512), 0, stream>>>(
      hb, W1t, b1, ff1o, nullptr, nullptr, nullptr, nullptr, MROWS, FF, HS, 0);

  // FF2: 8-phase split-K=3 — kSplit = 1408 = 11*128 (z2 gets 1280);
  // grid 4x16x3 = 192 blocks; f32 partials to 3 slabs (P2 = out).
  gemm8_bf16_kernel<false, false, true><<<dim3(4, 16, 3), dim3(512), 0, stream>>>(
      ff1o, W2t, nullptr, nullptr, nullptr, ff2P0, ff2P1, ff2P2,
      MROWS, HS, FF, 1408);
  add_ln_red3_kernel<<<dim3(MROWS), blk, 0, stream>>>(
      ff2P0, ff2P1, ff2P2, b2, h, g2, be2, out);
}